// Round 1
// baseline (4131.309 us; speedup 1.0000x reference)
//
#include <hip/hip_runtime.h>

typedef unsigned short u16;
typedef __attribute__((ext_vector_type(8))) short bf16x8;
typedef __attribute__((ext_vector_type(4))) float f32x4;

__device__ __forceinline__ u16 f2bf(float x){
  union { float f; unsigned u; } v; v.f = x;
  unsigned r = v.u + 0x7FFFu + ((v.u >> 16) & 1u);
  return (u16)(r >> 16);
}

// ---------- transpose + f32->bf16 convert: in (R,C) -> out (C,R) ----------
__global__ __launch_bounds__(256) void k_transpose_cvt(
    const float* __restrict__ in, u16* __restrict__ out,
    int R, int C, size_t in_ls, size_t out_ls){
  __shared__ float tile[32][33];
  in  += (size_t)blockIdx.z * in_ls;
  out += (size_t)blockIdx.z * out_ls;
  int c0 = blockIdx.x * 32, r0 = blockIdx.y * 32;
  int tx = threadIdx.x & 31, ty = threadIdx.x >> 5;  // ty 0..7
  #pragma unroll
  for (int i = 0; i < 32; i += 8)
    tile[ty + i][tx] = in[(size_t)(r0 + ty + i) * C + (c0 + tx)];
  __syncthreads();
  #pragma unroll
  for (int i = 0; i < 32; i += 8)
    out[(size_t)(c0 + ty + i) * R + (r0 + tx)] = f2bf(tile[tx][ty + i]);
}

// ---------- RMSNorm over D=1024, optional bf16 output ----------
__global__ __launch_bounds__(256) void k_rmsnorm(
    const float* __restrict__ x, const float* __restrict__ w,
    void* __restrict__ out, int out_bf16){
  int row = blockIdx.x;
  const float* xr = x + (size_t)row * 1024;
  int tid = threadIdx.x;
  float4 xv = ((const float4*)xr)[tid];
  float ss = xv.x*xv.x + xv.y*xv.y + xv.z*xv.z + xv.w*xv.w;
  #pragma unroll
  for (int off = 32; off >= 1; off >>= 1) ss += __shfl_xor(ss, off);
  __shared__ float red[4];
  if ((tid & 63) == 0) red[tid >> 6] = ss;
  __syncthreads();
  ss = red[0] + red[1] + red[2] + red[3];
  float s = rsqrtf(ss * (1.f/1024.f) + 1e-6f);
  float4 wv = ((const float4*)w)[tid];
  float o0 = xv.x*s*wv.x, o1 = xv.y*s*wv.y, o2 = xv.z*s*wv.z, o3 = xv.w*s*wv.w;
  if (out_bf16){
    u16* orow = (u16*)out + (size_t)row * 1024;
    uint2 pk;
    pk.x = (unsigned)f2bf(o0) | ((unsigned)f2bf(o1) << 16);
    pk.y = (unsigned)f2bf(o2) | ((unsigned)f2bf(o3) << 16);
    *(uint2*)(orow + tid * 4) = pk;
  } else {
    float* orow = (float*)out + (size_t)row * 1024;
    ((float4*)orow)[tid] = make_float4(o0, o1, o2, o3);
  }
}

// ---------- per-head RMSNorm (HD=64) + RoPE, in place, one wave per (token,head) ----------
__global__ __launch_bounds__(256) void k_qknorm_rope(
    float* __restrict__ x, const float* __restrict__ nw, int nheads, int rowstride){
  int gw = (blockIdx.x * 256 + threadIdx.x) >> 6;
  int lane = threadIdx.x & 63;
  int token = gw / nheads;
  int head = gw - token * nheads;
  int pos = token & 1023;  // S = 1024
  float* p = x + (size_t)token * rowstride + head * 64;
  float v = p[lane];
  float ss = v * v;
  #pragma unroll
  for (int off = 32; off >= 1; off >>= 1) ss += __shfl_xor(ss, off);
  float r = rsqrtf(ss * (1.f/64.f) + 1e-6f);
  float xn = v * r * nw[lane];
  float partner = __shfl_xor(xn, 32);
  int i = lane & 31;
  // inv = THETA^(-2i/64) = 2^(-log2(1e6) * 2i/64)
  float inv = exp2f(-19.931568569324174f * ((float)(2 * i) * (1.f/64.f)));
  float ang = (float)pos * inv;
  float sn, cs;
  sincosf(ang, &sn, &cs);
  float out = (lane < 32) ? (xn * cs - partner * sn) : (xn * cs + partner * sn);
  p[lane] = out;
}

// ---------- bf16 MFMA GEMM: C[M,N] = A[M,K] @ Bt[N,K]^T ----------
// epi: 0 = store f32, 1 = Cf += acc (residual), 2 = Cb = bf16(silu(Aux)*acc)
__global__ __launch_bounds__(256) void k_gemm(
    const u16* __restrict__ A, const u16* __restrict__ Bt,
    float* __restrict__ Cf, u16* __restrict__ Cb, const float* __restrict__ Aux,
    int M, int N, int K, int epi){
  __shared__ u16 As[128 * 32];
  __shared__ u16 Bs[128 * 32];
  int m0 = blockIdx.x * 128, n0 = blockIdx.y * 128;
  int tid = threadIdx.x;
  int lane = tid & 63, w = tid >> 6;
  int wm = w & 1, wn = w >> 1;
  int quad = lane >> 4, l16 = lane & 15;
  f32x4 acc[4][4];
  #pragma unroll
  for (int a = 0; a < 4; a++)
    #pragma unroll
    for (int b = 0; b < 4; b++) acc[a][b] = (f32x4){0.f, 0.f, 0.f, 0.f};

  for (int k0 = 0; k0 < K; k0 += 32){
    __syncthreads();
    #pragma unroll
    for (int i = 0; i < 2; i++){
      int ci = tid + i * 256;          // 512 chunks of 8 bf16 (16B)
      int row = ci >> 2, cc = ci & 3;
      *(uint4*)(&As[ci * 8]) = *(const uint4*)(A  + (size_t)(m0 + row) * K + k0 + cc * 8);
      *(uint4*)(&Bs[ci * 8]) = *(const uint4*)(Bt + (size_t)(n0 + row) * K + k0 + cc * 8);
    }
    __syncthreads();
    bf16x8 af[4], bg[4];
    #pragma unroll
    for (int mi = 0; mi < 4; mi++)
      af[mi] = *(const bf16x8*)&As[(wm * 64 + mi * 16 + l16) * 32 + quad * 8];
    #pragma unroll
    for (int ni = 0; ni < 4; ni++)
      bg[ni] = *(const bf16x8*)&Bs[(wn * 64 + ni * 16 + l16) * 32 + quad * 8];
    #pragma unroll
    for (int mi = 0; mi < 4; mi++)
      #pragma unroll
      for (int ni = 0; ni < 4; ni++)
        acc[mi][ni] = __builtin_amdgcn_mfma_f32_16x16x32_bf16(af[mi], bg[ni], acc[mi][ni], 0, 0, 0);
  }
  #pragma unroll
  for (int mi = 0; mi < 4; mi++){
    #pragma unroll
    for (int ni = 0; ni < 4; ni++){
      #pragma unroll
      for (int r = 0; r < 4; r++){
        int row = m0 + wm * 64 + mi * 16 + quad * 4 + r;
        int col = n0 + wn * 64 + ni * 16 + l16;
        size_t idx = (size_t)row * N + col;
        float vv = acc[mi][ni][r];
        if (epi == 0) Cf[idx] = vv;
        else if (epi == 1) Cf[idx] += vv;
        else {
          float g = Aux[idx];
          float sg = g / (1.f + __expf(-g));
          Cb[idx] = f2bf(sg * vv);
        }
      }
    }
  }
}

// ---------- fp32 flash attention, GQA (kv head = h>>1), writes bf16 ctx ----------
// q: (B*S, 16, 64) f32 ; kv: (B*S, 1024) f32 with k at cols [kh*64..], v at [512+kh*64..]
__global__ __launch_bounds__(256) void k_attn(
    const float* __restrict__ q, const float* __restrict__ kv,
    const int* __restrict__ am, u16* __restrict__ ctx, int window){
  const int S = 1024, H = 16;
  __shared__ float Qs[64][64];
  __shared__ float Ks[64][65];
  __shared__ float Ps[4][1024];
  int b = blockIdx.z, h = blockIdx.y, q0 = blockIdx.x * 64;
  int kh = h >> 1;
  int tid = threadIdx.x, w = tid >> 6, lane = tid & 63;

  // stage Q (64 rows x 64)
  #pragma unroll
  for (int i = 0; i < 4; i++){
    int c = tid + i * 256;
    int row = c >> 4, dc = (c & 15) * 4;
    float4 t = *(const float4*)(q + ((size_t)(b * S + q0 + row) * H + h) * 64 + dc);
    *(float4*)&Qs[row][dc] = t;
  }

  float m_[16], l_[16], o_[16];
  #pragma unroll
  for (int i = 0; i < 16; i++){ m_[i] = -1e30f; l_[i] = 0.f; o_[i] = 0.f; }

  int t0 = 0, t1 = S / 64;
  if (window < S){
    t0 = (q0 > window) ? ((q0 - window) >> 6) : 0;
    int last = q0 + 63 + window;
    int tt = last / 64 + 1;
    t1 = tt < (S / 64) ? tt : (S / 64);
  }

  for (int t = t0; t < t1; t++){
    __syncthreads();
    #pragma unroll
    for (int i = 0; i < 4; i++){
      int c = tid + i * 256;
      int row = c >> 4, dc = (c & 15) * 4;
      float4 tv = *(const float4*)(kv + (size_t)(b * S + t * 64 + row) * 1024 + kh * 64 + dc);
      Ks[row][dc + 0] = tv.x; Ks[row][dc + 1] = tv.y;
      Ks[row][dc + 2] = tv.z; Ks[row][dc + 3] = tv.w;
    }
    __syncthreads();

    int key = t * 64 + lane;
    bool kvalid = (am[b * S + key] > 0);
    float kreg[64];
    #pragma unroll
    for (int d = 0; d < 64; d++) kreg[d] = Ks[lane][d];

    #pragma unroll 4
    for (int qi = 0; qi < 16; qi++){
      int qq = q0 + w * 16 + qi;
      float s = 0.f;
      #pragma unroll
      for (int d = 0; d < 64; d++) s = fmaf(Qs[w * 16 + qi][d], kreg[d], s);
      s *= 0.125f;
      bool valid = kvalid && (abs(qq - key) <= window);
      float sm = valid ? s : -1e30f;
      float tmax = sm;
      #pragma unroll
      for (int off = 32; off >= 1; off >>= 1) tmax = fmaxf(tmax, __shfl_xor(tmax, off));
      float nm = fmaxf(m_[qi], tmax);
      float al = __expf(m_[qi] - nm);
      float p = valid ? __expf(sm - nm) : 0.f;
      float psum = p;
      #pragma unroll
      for (int off = 32; off >= 1; off >>= 1) psum += __shfl_xor(psum, off);
      l_[qi] = l_[qi] * al + psum;
      m_[qi] = nm;
      o_[qi] *= al;
      Ps[w][qi * 64 + lane] = p;
    }

    // PV: lane = d
    #pragma unroll 4
    for (int j = 0; j < 64; j++){
      float vd = kv[(size_t)(b * S + t * 64 + j) * 1024 + 512 + kh * 64 + lane];
      #pragma unroll
      for (int qi = 0; qi < 16; qi++)
        o_[qi] = fmaf(Ps[w][qi * 64 + j], vd, o_[qi]);
    }
  }

  #pragma unroll
  for (int qi = 0; qi < 16; qi++){
    int qq = q0 + w * 16 + qi;
    float ool = o_[qi] / fmaxf(l_[qi], 1e-30f);
    ctx[(size_t)(b * S + qq) * 1024 + h * 64 + lane] = f2bf(ool);
  }
}

extern "C" void kernel_launch(void* const* d_in, const int* in_sizes, int n_in,
                              void* d_out, int out_size, void* d_ws, size_t ws_size,
                              hipStream_t stream){
  const int L = 4, D = 1024, H = 16, HK = 8, HD = 64, FF = 3072, B = 4, S = 1024;
  const int M = B * S;  // 4096

  const float* emb = (const float*)d_in[0];
  const float* wq  = (const float*)d_in[1];
  const float* wk  = (const float*)d_in[2];
  const float* wv  = (const float*)d_in[3];
  const float* wo  = (const float*)d_in[4];
  const float* qnw = (const float*)d_in[5];
  const float* knw = (const float*)d_in[6];
  const float* ln1 = (const float*)d_in[7];
  const float* ln2 = (const float*)d_in[8];
  const float* wg  = (const float*)d_in[9];
  const float* wu  = (const float*)d_in[10];
  const float* wd  = (const float*)d_in[11];
  const float* nw  = (const float*)d_in[12];
  const int*   am  = (const int*)d_in[13];
  float* h = (float*)d_out;

  char* ws = (char*)d_ws;
  size_t off = 0;
  auto alloc = [&](size_t bytes) -> void* {
    void* p = ws + off;
    off += (bytes + 255) & ~(size_t)255;
    return p;
  };
  u16* wqT = (u16*)alloc((size_t)L * D * (H * HD) * 2);    // (L, 1024, 1024)
  u16* kvT = (u16*)alloc((size_t)L * 1024 * D * 2);        // (L, [k512|v512], 1024)
  u16* woT = (u16*)alloc((size_t)L * D * (H * HD) * 2);
  u16* wgT = (u16*)alloc((size_t)L * FF * D * 2);
  u16* wuT = (u16*)alloc((size_t)L * FF * D * 2);
  u16* wdT = (u16*)alloc((size_t)L * D * FF * 2);
  u16* nbf  = (u16*)alloc((size_t)M * D * 2);
  u16* ctxb = (u16*)alloc((size_t)M * D * 2);
  float* qb  = (float*)alloc((size_t)M * H * HD * 4);
  float* kvb = (float*)alloc((size_t)M * 1024 * 4);
  float* gate = (float*)alloc((size_t)M * FF * 4);
  u16* actb = (u16*)alloc((size_t)M * FF * 2);
  (void)ws_size; (void)in_sizes; (void)n_in; (void)out_size;

  hipMemcpyAsync(h, emb, (size_t)M * D * 4, hipMemcpyDeviceToDevice, stream);

  // weights -> bf16, transposed (N, K)
  k_transpose_cvt<<<dim3(32, 32, L), 256, 0, stream>>>(wq, wqT, D, 1024, (size_t)D*1024, (size_t)1024*D);
  k_transpose_cvt<<<dim3(16, 32, L), 256, 0, stream>>>(wk, kvT,             D, 512, (size_t)D*512, (size_t)1024*D);
  k_transpose_cvt<<<dim3(16, 32, L), 256, 0, stream>>>(wv, kvT + (size_t)512*D, D, 512, (size_t)D*512, (size_t)1024*D);
  k_transpose_cvt<<<dim3(32, 32, L), 256, 0, stream>>>(wo, woT, 1024, D, (size_t)1024*D, (size_t)D*1024);
  k_transpose_cvt<<<dim3(96, 32, L), 256, 0, stream>>>(wg, wgT, D, FF, (size_t)D*FF, (size_t)FF*D);
  k_transpose_cvt<<<dim3(96, 32, L), 256, 0, stream>>>(wu, wuT, D, FF, (size_t)D*FF, (size_t)FF*D);
  k_transpose_cvt<<<dim3(32, 96, L), 256, 0, stream>>>(wd, wdT, FF, D, (size_t)FF*D, (size_t)D*FF);

  for (int l = 0; l < L; l++){
    const u16* wqTl = wqT + (size_t)l * D * 1024;
    const u16* kvTl = kvT + (size_t)l * 1024 * D;
    const u16* woTl = woT + (size_t)l * D * 1024;
    const u16* wgTl = wgT + (size_t)l * FF * D;
    const u16* wuTl = wuT + (size_t)l * FF * D;
    const u16* wdTl = wdT + (size_t)l * D * FF;

    k_rmsnorm<<<M, 256, 0, stream>>>(h, ln1 + l * D, nbf, 1);
    k_gemm<<<dim3(M/128, 1024/128), 256, 0, stream>>>(nbf, wqTl, qb,  nullptr, nullptr, M, 1024, D, 0);
    k_gemm<<<dim3(M/128, 1024/128), 256, 0, stream>>>(nbf, kvTl, kvb, nullptr, nullptr, M, 1024, D, 0);
    k_qknorm_rope<<<(M * H) / 4, 256, 0, stream>>>(qb,  qnw + l * HD, H,  1024);
    k_qknorm_rope<<<(M * HK) / 4, 256, 0, stream>>>(kvb, knw + l * HD, HK, 1024);
    k_attn<<<dim3(S/64, H, B), 256, 0, stream>>>(qb, kvb, am, ctxb, (l & 1) ? 12 : 2048);
    k_gemm<<<dim3(M/128, 1024/128), 256, 0, stream>>>(ctxb, woTl, h, nullptr, nullptr, M, D, 1024, 1);
    k_rmsnorm<<<M, 256, 0, stream>>>(h, ln2 + l * D, nbf, 1);
    k_gemm<<<dim3(M/128, FF/128), 256, 0, stream>>>(nbf, wgTl, gate, nullptr, nullptr, M, FF, D, 0);
    k_gemm<<<dim3(M/128, FF/128), 256, 0, stream>>>(nbf, wuTl, nullptr, actb, gate, M, FF, D, 2);
    k_gemm<<<dim3(M/128, D/128), 256, 0, stream>>>(actb, wdTl, h, nullptr, nullptr, M, D, FF, 1);
  }
  k_rmsnorm<<<M, 256, 0, stream>>>(h, nw, h, 0);
}

// Round 2
// 1831.137 us; speedup vs baseline: 2.2561x; 2.2561x over previous
//
#include <hip/hip_runtime.h>

typedef unsigned short u16;
typedef __attribute__((ext_vector_type(8))) short bf16x8;
typedef __attribute__((ext_vector_type(4))) float f32x4;

__device__ __forceinline__ u16 f2bf(float x){
  union { float f; unsigned u; } v; v.f = x;
  unsigned r = v.u + 0x7FFFu + ((v.u >> 16) & 1u);
  return (u16)(r >> 16);
}
__device__ __forceinline__ float bf2f(u16 x){
  union { unsigned u; float f; } v; v.u = ((unsigned)x) << 16;
  return v.f;
}

// ---------- transpose + f32->bf16 convert: in (R,C) -> out rows = cols [c_off..) ----------
__global__ __launch_bounds__(256) void k_transpose_cvt(
    const float* __restrict__ in, u16* __restrict__ out,
    int R, int C, size_t in_ls, size_t out_ls, int c_off){
  __shared__ float tile[32][33];
  in  += (size_t)blockIdx.z * in_ls;
  out += (size_t)blockIdx.z * out_ls;
  int c0 = blockIdx.x * 32 + c_off, r0 = blockIdx.y * 32;
  int tx = threadIdx.x & 31, ty = threadIdx.x >> 5;  // ty 0..7
  #pragma unroll
  for (int i = 0; i < 32; i += 8)
    tile[ty + i][tx] = in[(size_t)(r0 + ty + i) * C + (c0 + tx)];
  __syncthreads();
  #pragma unroll
  for (int i = 0; i < 32; i += 8)
    out[(size_t)(c0 - c_off + ty + i) * R + (r0 + tx)] = f2bf(tile[tx][ty + i]);
}

// ---------- RMSNorm over D=1024, optional bf16 output ----------
__global__ __launch_bounds__(256) void k_rmsnorm(
    const float* __restrict__ x, const float* __restrict__ w,
    void* __restrict__ out, int out_bf16){
  int row = blockIdx.x;
  const float* xr = x + (size_t)row * 1024;
  int tid = threadIdx.x;
  float4 xv = ((const float4*)xr)[tid];
  float ss = xv.x*xv.x + xv.y*xv.y + xv.z*xv.z + xv.w*xv.w;
  #pragma unroll
  for (int off = 32; off >= 1; off >>= 1) ss += __shfl_xor(ss, off);
  __shared__ float red[4];
  if ((tid & 63) == 0) red[tid >> 6] = ss;
  __syncthreads();
  ss = red[0] + red[1] + red[2] + red[3];
  float s = rsqrtf(ss * (1.f/1024.f) + 1e-6f);
  float4 wv = ((const float4*)w)[tid];
  float o0 = xv.x*s*wv.x, o1 = xv.y*s*wv.y, o2 = xv.z*s*wv.z, o3 = xv.w*s*wv.w;
  if (out_bf16){
    u16* orow = (u16*)out + (size_t)row * 1024;
    uint2 pk;
    pk.x = (unsigned)f2bf(o0) | ((unsigned)f2bf(o1) << 16);
    pk.y = (unsigned)f2bf(o2) | ((unsigned)f2bf(o3) << 16);
    *(uint2*)(orow + tid * 4) = pk;
  } else {
    float* orow = (float*)out + (size_t)row * 1024;
    ((float4*)orow)[tid] = make_float4(o0, o1, o2, o3);
  }
}

// ---------- per-head RMSNorm (HD=64) + RoPE, f32 in -> bf16 out, one wave per (token,head) ----------
__global__ __launch_bounds__(256) void k_rope_bf16(
    const float* __restrict__ x, const float* __restrict__ nw,
    u16* __restrict__ dst, int nheads, int src_stride, int dst_stride){
  int gw = (blockIdx.x * 256 + threadIdx.x) >> 6;
  int lane = threadIdx.x & 63;
  int token = gw / nheads;
  int head = gw - token * nheads;
  int pos = token & 1023;  // S = 1024
  const float* p = x + (size_t)token * src_stride + head * 64;
  float v = p[lane];
  float ss = v * v;
  #pragma unroll
  for (int off = 32; off >= 1; off >>= 1) ss += __shfl_xor(ss, off);
  float r = rsqrtf(ss * (1.f/64.f) + 1e-6f);
  float xn = v * r * nw[lane];
  float partner = __shfl_xor(xn, 32);
  int i = lane & 31;
  float inv = exp2f(-19.931568569324174f * ((float)(2 * i) * (1.f/64.f)));
  float ang = (float)pos * inv;
  float sn, cs;
  sincosf(ang, &sn, &cs);
  float out = (lane < 32) ? (xn * cs - partner * sn) : (xn * cs + partner * sn);
  dst[(size_t)token * dst_stride + head * 64 + lane] = f2bf(out);
}

// ---------- bf16 MFMA GEMM: C[M,N] = A[M,K] @ Bt[N,K]^T ----------
// epi: 0 = store f32, 1 = Cf += acc (residual), 2 = Cb = bf16(silu(Aux)*acc)
__global__ __launch_bounds__(256) void k_gemm(
    const u16* __restrict__ A, const u16* __restrict__ Bt,
    float* __restrict__ Cf, u16* __restrict__ Cb, const float* __restrict__ Aux,
    int M, int N, int K, int epi){
  __shared__ u16 As[128 * 32];
  __shared__ u16 Bs[128 * 32];
  int m0 = blockIdx.x * 128, n0 = blockIdx.y * 128;
  int tid = threadIdx.x;
  int lane = tid & 63, w = tid >> 6;
  int wm = w & 1, wn = w >> 1;
  int quad = lane >> 4, l16 = lane & 15;
  f32x4 acc[4][4];
  #pragma unroll
  for (int a = 0; a < 4; a++)
    #pragma unroll
    for (int b = 0; b < 4; b++) acc[a][b] = (f32x4){0.f, 0.f, 0.f, 0.f};

  for (int k0 = 0; k0 < K; k0 += 32){
    __syncthreads();
    #pragma unroll
    for (int i = 0; i < 2; i++){
      int ci = tid + i * 256;          // 512 chunks of 8 bf16 (16B)
      int row = ci >> 2, cc = ci & 3;
      *(uint4*)(&As[ci * 8]) = *(const uint4*)(A  + (size_t)(m0 + row) * K + k0 + cc * 8);
      *(uint4*)(&Bs[ci * 8]) = *(const uint4*)(Bt + (size_t)(n0 + row) * K + k0 + cc * 8);
    }
    __syncthreads();
    bf16x8 af[4], bg[4];
    #pragma unroll
    for (int mi = 0; mi < 4; mi++)
      af[mi] = *(const bf16x8*)&As[(wm * 64 + mi * 16 + l16) * 32 + quad * 8];
    #pragma unroll
    for (int ni = 0; ni < 4; ni++)
      bg[ni] = *(const bf16x8*)&Bs[(wn * 64 + ni * 16 + l16) * 32 + quad * 8];
    #pragma unroll
    for (int mi = 0; mi < 4; mi++)
      #pragma unroll
      for (int ni = 0; ni < 4; ni++)
        acc[mi][ni] = __builtin_amdgcn_mfma_f32_16x16x32_bf16(af[mi], bg[ni], acc[mi][ni], 0, 0, 0);
  }
  #pragma unroll
  for (int mi = 0; mi < 4; mi++){
    #pragma unroll
    for (int ni = 0; ni < 4; ni++){
      #pragma unroll
      for (int r = 0; r < 4; r++){
        int row = m0 + wm * 64 + mi * 16 + quad * 4 + r;
        int col = n0 + wn * 64 + ni * 16 + l16;
        size_t idx = (size_t)row * N + col;
        float vv = acc[mi][ni][r];
        if (epi == 0) Cf[idx] = vv;
        else if (epi == 1) Cf[idx] += vv;
        else {
          float g = Aux[idx];
          float sg = g / (1.f + __expf(-g));
          Cb[idx] = f2bf(sg * vv);
        }
      }
    }
  }
}

// ---------- bf16 MFMA flash attention ----------
// qh: (B*S, 16, 64) bf16 ; kh_: (B*S, 8, 64) bf16 ; vth: (B, 8*64, S) bf16 (V transposed)
// block = (q-tile of 64, head, batch); 4 waves, wave w owns q rows w*16..w*16+15
__global__ __launch_bounds__(256) void k_attn(
    const u16* __restrict__ qh, const u16* __restrict__ kh_,
    const u16* __restrict__ vth, const int* __restrict__ am,
    u16* __restrict__ ctx, int window){
  const int S = 1024, H = 16, HK = 8;
  __shared__ u16 Qs[64 * 72];      // [q][d], stride 72 (144B = 9*16B aligned, bank-safe)
  __shared__ u16 Ks[64 * 72];      // [key][d]
  __shared__ u16 Vt[64 * 72];      // [d][key]
  __shared__ u16 Ps[4][16 * 72];   // per-wave P [q][key]
  __shared__ int Ams[64];
  int b = blockIdx.z, h = blockIdx.y, q0 = blockIdx.x * 64;
  int kvh = h >> 1;
  int tid = threadIdx.x, w = tid >> 6, lane = tid & 63;
  int quad = lane >> 4, l16 = lane & 15;

  // stage Q tile (64 x 64 bf16), coalesced 16B chunks
  #pragma unroll
  for (int i = 0; i < 2; i++){
    int c = tid + i * 256;
    int row = c >> 3, dc = (c & 7) * 8;
    *(uint4*)&Qs[row * 72 + dc] =
        *(const uint4*)(qh + ((size_t)(b * S + q0 + row) * H + h) * 64 + dc);
  }
  __syncthreads();
  bf16x8 aq[2];
  aq[0] = *(const bf16x8*)&Qs[(w * 16 + l16) * 72 + quad * 8];
  aq[1] = *(const bf16x8*)&Qs[(w * 16 + l16) * 72 + 32 + quad * 8];

  f32x4 o[4];
  #pragma unroll
  for (int di = 0; di < 4; di++) o[di] = (f32x4){0.f, 0.f, 0.f, 0.f};
  float m_[4], l_[4];
  #pragma unroll
  for (int r = 0; r < 4; r++){ m_[r] = -1e30f; l_[r] = 0.f; }

  int t0 = 0, t1 = S / 64;
  if (window < S){
    t0 = (q0 > window) ? ((q0 - window) >> 6) : 0;
    int tt = (q0 + 63 + window) / 64 + 1;
    t1 = tt < (S / 64) ? tt : (S / 64);
  }

  for (int t = t0; t < t1; t++){
    __syncthreads();  // previous tile's K/V reads done
    #pragma unroll
    for (int i = 0; i < 2; i++){
      int c = tid + i * 256;
      int row = c >> 3, dc = (c & 7) * 8;
      *(uint4*)&Ks[row * 72 + dc] =
          *(const uint4*)(kh_ + ((size_t)(b * S + t * 64 + row) * HK + kvh) * 64 + dc);
      // Vt tile rows are d, cols key: contiguous 64 tokens from vth
      *(uint4*)&Vt[row * 72 + dc] =
          *(const uint4*)(vth + ((size_t)b * 512 + kvh * 64 + row) * S + t * 64 + dc);
    }
    if (tid < 64) Ams[tid] = am[b * S + t * 64 + tid];
    __syncthreads();

    // QK^T: scores sc[ni] cover keys ni*16+l16, rows q = quad*4+r
    f32x4 sc[4];
    #pragma unroll
    for (int ni = 0; ni < 4; ni++){
      bf16x8 bk0 = *(const bf16x8*)&Ks[(ni * 16 + l16) * 72 + quad * 8];
      bf16x8 bk1 = *(const bf16x8*)&Ks[(ni * 16 + l16) * 72 + 32 + quad * 8];
      sc[ni] = __builtin_amdgcn_mfma_f32_16x16x32_bf16(aq[0], bk0, (f32x4){0.f,0.f,0.f,0.f}, 0, 0, 0);
      sc[ni] = __builtin_amdgcn_mfma_f32_16x16x32_bf16(aq[1], bk1, sc[ni], 0, 0, 0);
    }

    // mask + scale + row stats
    float rowmax[4];
    #pragma unroll
    for (int r = 0; r < 4; r++) rowmax[r] = -1e30f;
    #pragma unroll
    for (int ni = 0; ni < 4; ni++){
      int key = t * 64 + ni * 16 + l16;
      bool kval = Ams[ni * 16 + l16] > 0;
      #pragma unroll
      for (int r = 0; r < 4; r++){
        int qq = q0 + w * 16 + quad * 4 + r;
        int dlt = qq - key; if (dlt < 0) dlt = -dlt;
        bool valid = kval && (dlt <= window);
        float s = valid ? sc[ni][r] * 0.125f : -1e30f;
        sc[ni][r] = s;
        rowmax[r] = fmaxf(rowmax[r], s);
      }
    }
    #pragma unroll
    for (int off = 1; off <= 8; off <<= 1)
      #pragma unroll
      for (int r = 0; r < 4; r++) rowmax[r] = fmaxf(rowmax[r], __shfl_xor(rowmax[r], off));

    float alpha[4], rsum[4];
    #pragma unroll
    for (int r = 0; r < 4; r++){
      float nm = fmaxf(m_[r], rowmax[r]);
      alpha[r] = __expf(m_[r] - nm);
      m_[r] = nm;
      rsum[r] = 0.f;
    }
    #pragma unroll
    for (int ni = 0; ni < 4; ni++){
      #pragma unroll
      for (int r = 0; r < 4; r++){
        float s = sc[ni][r];
        float p = (s == -1e30f) ? 0.f : __expf(s - m_[r]);
        u16 pb = f2bf(p);
        rsum[r] += bf2f(pb);  // keep l consistent with bf16-rounded P
        Ps[w][(quad * 4 + r) * 72 + ni * 16 + l16] = pb;
      }
    }
    #pragma unroll
    for (int off = 1; off <= 8; off <<= 1)
      #pragma unroll
      for (int r = 0; r < 4; r++) rsum[r] += __shfl_xor(rsum[r], off);
    #pragma unroll
    for (int r = 0; r < 4; r++) l_[r] = l_[r] * alpha[r] + rsum[r];
    #pragma unroll
    for (int di = 0; di < 4; di++)
      #pragma unroll
      for (int r = 0; r < 4; r++) o[di][r] *= alpha[r];

    __syncthreads();  // Ps visible

    // P @ V: A = P rows (q), B = Vt rows (d)
    bf16x8 ap0 = *(const bf16x8*)&Ps[w][l16 * 72 + quad * 8];
    bf16x8 ap1 = *(const bf16x8*)&Ps[w][l16 * 72 + 32 + quad * 8];
    #pragma unroll
    for (int di = 0; di < 4; di++){
      bf16x8 bv0 = *(const bf16x8*)&Vt[(di * 16 + l16) * 72 + quad * 8];
      bf16x8 bv1 = *(const bf16x8*)&Vt[(di * 16 + l16) * 72 + 32 + quad * 8];
      o[di] = __builtin_amdgcn_mfma_f32_16x16x32_bf16(ap0, bv0, o[di], 0, 0, 0);
      o[di] = __builtin_amdgcn_mfma_f32_16x16x32_bf16(ap1, bv1, o[di], 0, 0, 0);
    }
  }

  #pragma unroll
  for (int di = 0; di < 4; di++){
    #pragma unroll
    for (int r = 0; r < 4; r++){
      int qq = q0 + w * 16 + quad * 4 + r;
      float val = o[di][r] / fmaxf(l_[r], 1e-30f);
      ctx[(size_t)(b * S + qq) * 1024 + h * 64 + di * 16 + l16] = f2bf(val);
    }
  }
}

extern "C" void kernel_launch(void* const* d_in, const int* in_sizes, int n_in,
                              void* d_out, int out_size, void* d_ws, size_t ws_size,
                              hipStream_t stream){
  const int L = 4, D = 1024, H = 16, HK = 8, HD = 64, FF = 3072, B = 4, S = 1024;
  const int M = B * S;  // 4096

  const float* emb = (const float*)d_in[0];
  const float* wq  = (const float*)d_in[1];
  const float* wk  = (const float*)d_in[2];
  const float* wv  = (const float*)d_in[3];
  const float* wo  = (const float*)d_in[4];
  const float* qnw = (const float*)d_in[5];
  const float* knw = (const float*)d_in[6];
  const float* ln1 = (const float*)d_in[7];
  const float* ln2 = (const float*)d_in[8];
  const float* wg  = (const float*)d_in[9];
  const float* wu  = (const float*)d_in[10];
  const float* wd  = (const float*)d_in[11];
  const float* nw  = (const float*)d_in[12];
  const int*   am  = (const int*)d_in[13];
  float* h = (float*)d_out;

  char* ws = (char*)d_ws;
  size_t off = 0;
  auto alloc = [&](size_t bytes) -> void* {
    void* p = ws + off;
    off += (bytes + 255) & ~(size_t)255;
    return p;
  };
  u16* wqT = (u16*)alloc((size_t)L * D * (H * HD) * 2);    // (L, 1024, 1024)
  u16* kvT = (u16*)alloc((size_t)L * 1024 * D * 2);        // (L, [k512|v512], 1024)
  u16* woT = (u16*)alloc((size_t)L * D * (H * HD) * 2);
  u16* wgT = (u16*)alloc((size_t)L * FF * D * 2);
  u16* wuT = (u16*)alloc((size_t)L * FF * D * 2);
  u16* wdT = (u16*)alloc((size_t)L * D * FF * 2);
  u16* nbf  = (u16*)alloc((size_t)M * D * 2);
  u16* ctxb = (u16*)alloc((size_t)M * D * 2);
  float* qb  = (float*)alloc((size_t)M * H * HD * 4);
  float* kvb = (float*)alloc((size_t)M * 1024 * 4);
  float* gate = (float*)alloc((size_t)M * FF * 4);
  u16* actb = (u16*)alloc((size_t)M * FF * 2);
  (void)ws_size; (void)in_sizes; (void)n_in; (void)out_size;

  // attention bf16 buffers alias the gate region (disjoint lifetimes)
  u16* qbh = (u16*)gate;                              // M*1024 bf16 = 8 MB
  u16* kbh = (u16*)((char*)gate + (size_t)8 * 1024 * 1024);  // M*512 bf16 = 4 MB
  u16* vth = (u16*)((char*)gate + (size_t)12 * 1024 * 1024); // B*512*S bf16 = 4 MB

  hipMemcpyAsync(h, emb, (size_t)M * D * 4, hipMemcpyDeviceToDevice, stream);

  // weights -> bf16, transposed (N, K)
  k_transpose_cvt<<<dim3(32, 32, L), 256, 0, stream>>>(wq, wqT, D, 1024, (size_t)D*1024, (size_t)1024*D, 0);
  k_transpose_cvt<<<dim3(16, 32, L), 256, 0, stream>>>(wk, kvT,             D, 512, (size_t)D*512, (size_t)1024*D, 0);
  k_transpose_cvt<<<dim3(16, 32, L), 256, 0, stream>>>(wv, kvT + (size_t)512*D, D, 512, (size_t)D*512, (size_t)1024*D, 0);
  k_transpose_cvt<<<dim3(32, 32, L), 256, 0, stream>>>(wo, woT, 1024, D, (size_t)1024*D, (size_t)D*1024, 0);
  k_transpose_cvt<<<dim3(96, 32, L), 256, 0, stream>>>(wg, wgT, D, FF, (size_t)D*FF, (size_t)FF*D, 0);
  k_transpose_cvt<<<dim3(96, 32, L), 256, 0, stream>>>(wu, wuT, D, FF, (size_t)D*FF, (size_t)FF*D, 0);
  k_transpose_cvt<<<dim3(32, 96, L), 256, 0, stream>>>(wd, wdT, FF, D, (size_t)FF*D, (size_t)D*FF, 0);

  for (int l = 0; l < L; l++){
    const u16* wqTl = wqT + (size_t)l * D * 1024;
    const u16* kvTl = kvT + (size_t)l * 1024 * D;
    const u16* woTl = woT + (size_t)l * D * 1024;
    const u16* wgTl = wgT + (size_t)l * FF * D;
    const u16* wuTl = wuT + (size_t)l * FF * D;
    const u16* wdTl = wdT + (size_t)l * D * FF;

    k_rmsnorm<<<M, 256, 0, stream>>>(h, ln1 + l * D, nbf, 1);
    k_gemm<<<dim3(M/128, 1024/128), 256, 0, stream>>>(nbf, wqTl, qb,  nullptr, nullptr, M, 1024, D, 0);
    k_gemm<<<dim3(M/128, 1024/128), 256, 0, stream>>>(nbf, kvTl, kvb, nullptr, nullptr, M, 1024, D, 0);
    // q/k: head-RMSNorm + RoPE -> bf16 ; v: transpose -> (B, 512, S) bf16
    k_rope_bf16<<<(M * H) / 4, 256, 0, stream>>>(qb,  qnw + l * HD, qbh, H,  1024, 1024);
    k_rope_bf16<<<(M * HK) / 4, 256, 0, stream>>>(kvb, knw + l * HD, kbh, HK, 1024, 512);
    k_transpose_cvt<<<dim3(16, 32, B), 256, 0, stream>>>(kvb, vth, S, 1024, (size_t)S*1024, (size_t)512*S, 512);
    k_attn<<<dim3(S/64, H, B), 256, 0, stream>>>(qbh, kbh, vth, am, ctxb, (l & 1) ? 12 : 2048);
    k_gemm<<<dim3(M/128, 1024/128), 256, 0, stream>>>(ctxb, woTl, h, nullptr, nullptr, M, D, 1024, 1);
    k_rmsnorm<<<M, 256, 0, stream>>>(h, ln2 + l * D, nbf, 1);
    k_gemm<<<dim3(M/128, FF/128), 256, 0, stream>>>(nbf, wgTl, gate, nullptr, nullptr, M, FF, D, 0);
    k_gemm<<<dim3(M/128, FF/128), 256, 0, stream>>>(nbf, wuTl, nullptr, actb, gate, M, FF, D, 2);
    k_gemm<<<dim3(M/128, D/128), 256, 0, stream>>>(actb, wdTl, h, nullptr, nullptr, M, D, FF, 1);
  }
  k_rmsnorm<<<M, 256, 0, stream>>>(h, nw, h, 0);
}

// Round 3
// 1702.163 us; speedup vs baseline: 2.4271x; 1.0758x over previous
//
#include <hip/hip_runtime.h>

typedef unsigned short u16;
typedef __attribute__((ext_vector_type(8))) short bf16x8;
typedef __attribute__((ext_vector_type(4))) float f32x4;

__device__ __forceinline__ u16 f2bf(float x){
  union { float f; unsigned u; } v; v.f = x;
  unsigned r = v.u + 0x7FFFu + ((v.u >> 16) & 1u);
  return (u16)(r >> 16);
}
__device__ __forceinline__ float bf2f(u16 x){
  union { unsigned u; float f; } v; v.u = ((unsigned)x) << 16;
  return v.f;
}
// async global->LDS, 16B per lane; lds dest must be wave-uniform base + lane*16
__device__ __forceinline__ void async16(const u16* g, u16* l){
  __builtin_amdgcn_global_load_lds((const __attribute__((address_space(1))) void*)g,
                                   (__attribute__((address_space(3))) void*)l, 16, 0, 0);
}

// ---------- transpose + f32->bf16 convert: out rows = in cols [c_off..) ----------
__global__ __launch_bounds__(256) void k_transpose_cvt(
    const float* __restrict__ in, u16* __restrict__ out,
    int R, int C, size_t in_ls, size_t out_ls, int c_off){
  __shared__ float tile[32][33];
  in  += (size_t)blockIdx.z * in_ls;
  out += (size_t)blockIdx.z * out_ls;
  int c0 = blockIdx.x * 32 + c_off, r0 = blockIdx.y * 32;
  int tx = threadIdx.x & 31, ty = threadIdx.x >> 5;  // ty 0..7
  #pragma unroll
  for (int i = 0; i < 32; i += 8)
    tile[ty + i][tx] = in[(size_t)(r0 + ty + i) * C + (c0 + tx)];
  __syncthreads();
  #pragma unroll
  for (int i = 0; i < 32; i += 8)
    out[(size_t)(c0 - c_off + ty + i) * R + (r0 + tx)] = f2bf(tile[tx][ty + i]);
}

// ---------- RMSNorm over D=1024, optional bf16 output ----------
__global__ __launch_bounds__(256) void k_rmsnorm(
    const float* __restrict__ x, const float* __restrict__ w,
    void* __restrict__ out, int out_bf16){
  int row = blockIdx.x;
  const float* xr = x + (size_t)row * 1024;
  int tid = threadIdx.x;
  float4 xv = ((const float4*)xr)[tid];
  float ss = xv.x*xv.x + xv.y*xv.y + xv.z*xv.z + xv.w*xv.w;
  #pragma unroll
  for (int off = 32; off >= 1; off >>= 1) ss += __shfl_xor(ss, off);
  __shared__ float red[4];
  if ((tid & 63) == 0) red[tid >> 6] = ss;
  __syncthreads();
  ss = red[0] + red[1] + red[2] + red[3];
  float s = rsqrtf(ss * (1.f/1024.f) + 1e-6f);
  float4 wv = ((const float4*)w)[tid];
  float o0 = xv.x*s*wv.x, o1 = xv.y*s*wv.y, o2 = xv.z*s*wv.z, o3 = xv.w*s*wv.w;
  if (out_bf16){
    u16* orow = (u16*)out + (size_t)row * 1024;
    uint2 pk;
    pk.x = (unsigned)f2bf(o0) | ((unsigned)f2bf(o1) << 16);
    pk.y = (unsigned)f2bf(o2) | ((unsigned)f2bf(o3) << 16);
    *(uint2*)(orow + tid * 4) = pk;
  } else {
    float* orow = (float*)out + (size_t)row * 1024;
    ((float4*)orow)[tid] = make_float4(o0, o1, o2, o3);
  }
}

// ---------- per-head RMSNorm (HD=64) + RoPE, f32 in -> bf16 out, one wave per (token,head) ----------
__global__ __launch_bounds__(256) void k_rope_bf16(
    const float* __restrict__ x, const float* __restrict__ nw,
    u16* __restrict__ dst, int nheads, int src_stride, int dst_stride){
  int gw = (blockIdx.x * 256 + threadIdx.x) >> 6;
  int lane = threadIdx.x & 63;
  int token = gw / nheads;
  int head = gw - token * nheads;
  int pos = token & 1023;  // S = 1024
  const float* p = x + (size_t)token * src_stride + head * 64;
  float v = p[lane];
  float ss = v * v;
  #pragma unroll
  for (int off = 32; off >= 1; off >>= 1) ss += __shfl_xor(ss, off);
  float r = rsqrtf(ss * (1.f/64.f) + 1e-6f);
  float xn = v * r * nw[lane];
  float partner = __shfl_xor(xn, 32);
  int i = lane & 31;
  float inv = exp2f(-19.931568569324174f * ((float)(2 * i) * (1.f/64.f)));
  float ang = (float)pos * inv;
  float sn, cs;
  sincosf(ang, &sn, &cs);
  float out = (lane < 32) ? (xn * cs - partner * sn) : (xn * cs + partner * sn);
  dst[(size_t)token * dst_stride + head * 64 + lane] = f2bf(out);
}

// ---------- bf16 MFMA GEMM, async-staged: C[M,N] = A[M,K] @ Bt[N,K]^T ----------
// epi: 0 = store f32, 1 = Cf += acc (residual), 2 = Cb = bf16(silu(Aux)*acc)
__global__ __launch_bounds__(256) void k_gemm(
    const u16* __restrict__ A, const u16* __restrict__ Bt,
    float* __restrict__ Cf, u16* __restrict__ Cb, const float* __restrict__ Aux,
    int M, int N, int K, int epi){
  __shared__ u16 As[128 * 32];   // 512 chunks of 16B
  __shared__ u16 Bs[128 * 32];
  int m0 = blockIdx.x * 128, n0 = blockIdx.y * 128;
  int tid = threadIdx.x;
  int lane = tid & 63, w = tid >> 6;
  int wm = w & 1, wn = w >> 1;
  int quad = lane >> 4, l16 = lane & 15;
  f32x4 acc[4][4];
  #pragma unroll
  for (int a = 0; a < 4; a++)
    #pragma unroll
    for (int b = 0; b < 4; b++) acc[a][b] = (f32x4){0.f, 0.f, 0.f, 0.f};

  for (int k0 = 0; k0 < K; k0 += 32){
    __syncthreads();
    // wave w owns chunks [w*128, w*128+128) of each tile; lds dest = uniform base + lane*16
    #pragma unroll
    for (int j = 0; j < 2; j++){
      int cb = w * 128 + j * 64;
      int ci = cb + lane;
      int row = ci >> 2, cc = ci & 3;
      async16(A  + (size_t)(m0 + row) * K + k0 + cc * 8, &As[cb * 8]);
      async16(Bt + (size_t)(n0 + row) * K + k0 + cc * 8, &Bs[cb * 8]);
    }
    __syncthreads();  // drains vmcnt (global_load_lds) before any frag read
    bf16x8 af[4], bg[4];
    #pragma unroll
    for (int mi = 0; mi < 4; mi++)
      af[mi] = *(const bf16x8*)&As[(wm * 64 + mi * 16 + l16) * 32 + quad * 8];
    #pragma unroll
    for (int ni = 0; ni < 4; ni++)
      bg[ni] = *(const bf16x8*)&Bs[(wn * 64 + ni * 16 + l16) * 32 + quad * 8];
    #pragma unroll
    for (int mi = 0; mi < 4; mi++)
      #pragma unroll
      for (int ni = 0; ni < 4; ni++)
        acc[mi][ni] = __builtin_amdgcn_mfma_f32_16x16x32_bf16(af[mi], bg[ni], acc[mi][ni], 0, 0, 0);
  }
  #pragma unroll
  for (int mi = 0; mi < 4; mi++){
    #pragma unroll
    for (int ni = 0; ni < 4; ni++){
      #pragma unroll
      for (int r = 0; r < 4; r++){
        int row = m0 + wm * 64 + mi * 16 + quad * 4 + r;
        int col = n0 + wn * 64 + ni * 16 + l16;
        size_t idx = (size_t)row * N + col;
        float vv = acc[mi][ni][r];
        if (epi == 0) Cf[idx] = vv;
        else if (epi == 1) Cf[idx] += vv;
        else {
          float g = Aux[idx];
          float sg = g / (1.f + __expf(-g));
          Cb[idx] = f2bf(sg * vv);
        }
      }
    }
  }
}

// ---------- bf16 MFMA flash attention ----------
// qh: (B*S, 16, 64) bf16 ; kh_: (B*S, 8, 64) bf16 ; vth: (B, 8*64, S) bf16 (V transposed)
__global__ __launch_bounds__(256) void k_attn(
    const u16* __restrict__ qh, const u16* __restrict__ kh_,
    const u16* __restrict__ vth, const int* __restrict__ am,
    u16* __restrict__ ctx, int window){
  const int S = 1024, H = 16, HK = 8;
  __shared__ u16 Qs[64 * 72];      // [q][d], stride 72 (bank-safe)
  __shared__ u16 Ks[64 * 72];      // [key][d]
  __shared__ u16 Vt[64 * 72];      // [d][key]
  __shared__ u16 Ps[4][16 * 72];   // per-wave P [q][key]
  __shared__ int Ams[64];
  int b = blockIdx.z, h = blockIdx.y, q0 = blockIdx.x * 64;
  int kvh = h >> 1;
  int tid = threadIdx.x, w = tid >> 6, lane = tid & 63;
  int quad = lane >> 4, l16 = lane & 15;

  #pragma unroll
  for (int i = 0; i < 2; i++){
    int c = tid + i * 256;
    int row = c >> 3, dc = (c & 7) * 8;
    *(uint4*)&Qs[row * 72 + dc] =
        *(const uint4*)(qh + ((size_t)(b * S + q0 + row) * H + h) * 64 + dc);
  }
  __syncthreads();
  bf16x8 aq[2];
  aq[0] = *(const bf16x8*)&Qs[(w * 16 + l16) * 72 + quad * 8];
  aq[1] = *(const bf16x8*)&Qs[(w * 16 + l16) * 72 + 32 + quad * 8];

  f32x4 o[4];
  #pragma unroll
  for (int di = 0; di < 4; di++) o[di] = (f32x4){0.f, 0.f, 0.f, 0.f};
  float m_[4], l_[4];
  #pragma unroll
  for (int r = 0; r < 4; r++){ m_[r] = -1e30f; l_[r] = 0.f; }

  int t0 = 0, t1 = S / 64;
  if (window < S){
    t0 = (q0 > window) ? ((q0 - window) >> 6) : 0;
    int tt = (q0 + 63 + window) / 64 + 1;
    t1 = tt < (S / 64) ? tt : (S / 64);
  }

  for (int t = t0; t < t1; t++){
    __syncthreads();
    #pragma unroll
    for (int i = 0; i < 2; i++){
      int c = tid + i * 256;
      int row = c >> 3, dc = (c & 7) * 8;
      *(uint4*)&Ks[row * 72 + dc] =
          *(const uint4*)(kh_ + ((size_t)(b * S + t * 64 + row) * HK + kvh) * 64 + dc);
      *(uint4*)&Vt[row * 72 + dc] =
          *(const uint4*)(vth + ((size_t)b * 512 + kvh * 64 + row) * S + t * 64 + dc);
    }
    if (tid < 64) Ams[tid] = am[b * S + t * 64 + tid];
    __syncthreads();

    f32x4 sc[4];
    #pragma unroll
    for (int ni = 0; ni < 4; ni++){
      bf16x8 bk0 = *(const bf16x8*)&Ks[(ni * 16 + l16) * 72 + quad * 8];
      bf16x8 bk1 = *(const bf16x8*)&Ks[(ni * 16 + l16) * 72 + 32 + quad * 8];
      sc[ni] = __builtin_amdgcn_mfma_f32_16x16x32_bf16(aq[0], bk0, (f32x4){0.f,0.f,0.f,0.f}, 0, 0, 0);
      sc[ni] = __builtin_amdgcn_mfma_f32_16x16x32_bf16(aq[1], bk1, sc[ni], 0, 0, 0);
    }

    float rowmax[4];
    #pragma unroll
    for (int r = 0; r < 4; r++) rowmax[r] = -1e30f;
    #pragma unroll
    for (int ni = 0; ni < 4; ni++){
      int key = t * 64 + ni * 16 + l16;
      bool kval = Ams[ni * 16 + l16] > 0;
      #pragma unroll
      for (int r = 0; r < 4; r++){
        int qq = q0 + w * 16 + quad * 4 + r;
        int dlt = qq - key; if (dlt < 0) dlt = -dlt;
        bool valid = kval && (dlt <= window);
        float s = valid ? sc[ni][r] * 0.125f : -1e30f;
        sc[ni][r] = s;
        rowmax[r] = fmaxf(rowmax[r], s);
      }
    }
    #pragma unroll
    for (int off = 1; off <= 8; off <<= 1)
      #pragma unroll
      for (int r = 0; r < 4; r++) rowmax[r] = fmaxf(rowmax[r], __shfl_xor(rowmax[r], off));

    float alpha[4], rsum[4];
    #pragma unroll
    for (int r = 0; r < 4; r++){
      float nm = fmaxf(m_[r], rowmax[r]);
      alpha[r] = __expf(m_[r] - nm);
      m_[r] = nm;
      rsum[r] = 0.f;
    }
    #pragma unroll
    for (int ni = 0; ni < 4; ni++){
      #pragma unroll
      for (int r = 0; r < 4; r++){
        float s = sc[ni][r];
        float p = (s == -1e30f) ? 0.f : __expf(s - m_[r]);
        u16 pb = f2bf(p);
        rsum[r] += bf2f(pb);
        Ps[w][(quad * 4 + r) * 72 + ni * 16 + l16] = pb;
      }
    }
    #pragma unroll
    for (int off = 1; off <= 8; off <<= 1)
      #pragma unroll
      for (int r = 0; r < 4; r++) rsum[r] += __shfl_xor(rsum[r], off);
    #pragma unroll
    for (int r = 0; r < 4; r++) l_[r] = l_[r] * alpha[r] + rsum[r];
    #pragma unroll
    for (int di = 0; di < 4; di++)
      #pragma unroll
      for (int r = 0; r < 4; r++) o[di][r] *= alpha[r];

    __syncthreads();

    bf16x8 ap0 = *(const bf16x8*)&Ps[w][l16 * 72 + quad * 8];
    bf16x8 ap1 = *(const bf16x8*)&Ps[w][l16 * 72 + 32 + quad * 8];
    #pragma unroll
    for (int di = 0; di < 4; di++){
      bf16x8 bv0 = *(const bf16x8*)&Vt[(di * 16 + l16) * 72 + quad * 8];
      bf16x8 bv1 = *(const bf16x8*)&Vt[(di * 16 + l16) * 72 + 32 + quad * 8];
      o[di] = __builtin_amdgcn_mfma_f32_16x16x32_bf16(ap0, bv0, o[di], 0, 0, 0);
      o[di] = __builtin_amdgcn_mfma_f32_16x16x32_bf16(ap1, bv1, o[di], 0, 0, 0);
    }
  }

  #pragma unroll
  for (int di = 0; di < 4; di++){
    #pragma unroll
    for (int r = 0; r < 4; r++){
      int qq = q0 + w * 16 + quad * 4 + r;
      float val = o[di][r] / fmaxf(l_[r], 1e-30f);
      ctx[(size_t)(b * S + qq) * 1024 + h * 64 + di * 16 + l16] = f2bf(val);
    }
  }
}

extern "C" void kernel_launch(void* const* d_in, const int* in_sizes, int n_in,
                              void* d_out, int out_size, void* d_ws, size_t ws_size,
                              hipStream_t stream){
  const int L = 4, D = 1024, H = 16, HK = 8, HD = 64, FF = 3072, B = 4, S = 1024;
  const int M = B * S;  // 4096

  const float* emb = (const float*)d_in[0];
  const float* wq  = (const float*)d_in[1];
  const float* wk  = (const float*)d_in[2];
  const float* wv  = (const float*)d_in[3];
  const float* wo  = (const float*)d_in[4];
  const float* qnw = (const float*)d_in[5];
  const float* knw = (const float*)d_in[6];
  const float* ln1 = (const float*)d_in[7];
  const float* ln2 = (const float*)d_in[8];
  const float* wg  = (const float*)d_in[9];
  const float* wu  = (const float*)d_in[10];
  const float* wd  = (const float*)d_in[11];
  const float* nw  = (const float*)d_in[12];
  const int*   am  = (const int*)d_in[13];
  float* h = (float*)d_out;

  char* ws = (char*)d_ws;
  size_t off = 0;
  auto alloc = [&](size_t bytes) -> void* {
    void* p = ws + off;
    off += (bytes + 255) & ~(size_t)255;
    return p;
  };
  u16* wqkvT = (u16*)alloc((size_t)L * 2048 * D * 2);  // rows: [q 1024 | k 512 | v 512], K-major
  u16* woT = (u16*)alloc((size_t)L * D * (H * HD) * 2);
  u16* wgT = (u16*)alloc((size_t)L * FF * D * 2);
  u16* wuT = (u16*)alloc((size_t)L * FF * D * 2);
  u16* wdT = (u16*)alloc((size_t)L * D * FF * 2);
  u16* nbf  = (u16*)alloc((size_t)M * D * 2);
  u16* ctxb = (u16*)alloc((size_t)M * D * 2);
  float* qkvb = (float*)alloc((size_t)M * 2048 * 4);  // [q 1024 | k 512 | v 512]
  float* gate = (float*)alloc((size_t)M * FF * 4);
  u16* actb = (u16*)alloc((size_t)M * FF * 2);
  (void)ws_size; (void)in_sizes; (void)n_in; (void)out_size;

  // attention bf16 buffers alias the gate region (disjoint lifetimes)
  u16* qbh = (u16*)gate;                                     // M*1024 bf16 = 8 MB
  u16* kbh = (u16*)((char*)gate + (size_t)8 * 1024 * 1024);  // M*512 bf16 = 4 MB
  u16* vth = (u16*)((char*)gate + (size_t)12 * 1024 * 1024); // B*512*S bf16 = 4 MB

  hipMemcpyAsync(h, emb, (size_t)M * D * 4, hipMemcpyDeviceToDevice, stream);

  // weights -> bf16, transposed (N, K); q/k/v stacked into one (2048, 1024) matrix
  k_transpose_cvt<<<dim3(32, 32, L), 256, 0, stream>>>(wq, wqkvT,                      D, 1024, (size_t)D*1024, (size_t)2048*D, 0);
  k_transpose_cvt<<<dim3(16, 32, L), 256, 0, stream>>>(wk, wqkvT + (size_t)1024*D,     D, 512,  (size_t)D*512,  (size_t)2048*D, 0);
  k_transpose_cvt<<<dim3(16, 32, L), 256, 0, stream>>>(wv, wqkvT + (size_t)1536*D,     D, 512,  (size_t)D*512,  (size_t)2048*D, 0);
  k_transpose_cvt<<<dim3(32, 32, L), 256, 0, stream>>>(wo, woT, 1024, D, (size_t)1024*D, (size_t)D*1024, 0);
  k_transpose_cvt<<<dim3(96, 32, L), 256, 0, stream>>>(wg, wgT, D, FF, (size_t)D*FF, (size_t)FF*D, 0);
  k_transpose_cvt<<<dim3(96, 32, L), 256, 0, stream>>>(wu, wuT, D, FF, (size_t)D*FF, (size_t)FF*D, 0);
  k_transpose_cvt<<<dim3(32, 96, L), 256, 0, stream>>>(wd, wdT, FF, D, (size_t)FF*D, (size_t)D*FF, 0);

  for (int l = 0; l < L; l++){
    const u16* wqkvTl = wqkvT + (size_t)l * 2048 * D;
    const u16* woTl = woT + (size_t)l * D * 1024;
    const u16* wgTl = wgT + (size_t)l * FF * D;
    const u16* wuTl = wuT + (size_t)l * FF * D;
    const u16* wdTl = wdT + (size_t)l * D * FF;

    k_rmsnorm<<<M, 256, 0, stream>>>(h, ln1 + l * D, nbf, 1);
    k_gemm<<<dim3(M/128, 2048/128), 256, 0, stream>>>(nbf, wqkvTl, qkvb, nullptr, nullptr, M, 2048, D, 0);
    k_rope_bf16<<<(M * H) / 4, 256, 0, stream>>>(qkvb,        qnw + l * HD, qbh, H,  2048, 1024);
    k_rope_bf16<<<(M * HK) / 4, 256, 0, stream>>>(qkvb + 1024, knw + l * HD, kbh, HK, 2048, 512);
    k_transpose_cvt<<<dim3(16, 32, B), 256, 0, stream>>>(qkvb, vth, S, 2048, (size_t)S*2048, (size_t)512*S, 1536);
    k_attn<<<dim3(S/64, H, B), 256, 0, stream>>>(qbh, kbh, vth, am, ctxb, (l & 1) ? 12 : 2048);
    k_gemm<<<dim3(M/128, 1024/128), 256, 0, stream>>>(ctxb, woTl, h, nullptr, nullptr, M, D, 1024, 1);
    k_rmsnorm<<<M, 256, 0, stream>>>(h, ln2 + l * D, nbf, 1);
    k_gemm<<<dim3(M/128, FF/128), 256, 0, stream>>>(nbf, wgTl, gate, nullptr, nullptr, M, FF, D, 0);
    k_gemm<<<dim3(M/128, FF/128), 256, 0, stream>>>(nbf, wuTl, nullptr, actb, gate, M, FF, D, 2);
    k_gemm<<<dim3(M/128, D/128), 256, 0, stream>>>(actb, wdTl, h, nullptr, nullptr, M, D, FF, 1);
  }
  k_rmsnorm<<<M, 256, 0, stream>>>(h, nw, h, 0);
}

// Round 4
// 1438.721 us; speedup vs baseline: 2.8715x; 1.1831x over previous
//
#include <hip/hip_runtime.h>

typedef unsigned short u16;
typedef __attribute__((ext_vector_type(8))) short bf16x8;
typedef __attribute__((ext_vector_type(4))) float f32x4;

__device__ __forceinline__ u16 f2bf(float x){
  union { float f; unsigned u; } v; v.f = x;
  unsigned r = v.u + 0x7FFFu + ((v.u >> 16) & 1u);
  return (u16)(r >> 16);
}
__device__ __forceinline__ float bf2f(u16 x){
  union { unsigned u; float f; } v; v.u = ((unsigned)x) << 16;
  return v.f;
}
// async global->LDS, 16B per lane; lds dest must be wave-uniform base + lane*16
__device__ __forceinline__ void async16(const u16* g, u16* l){
  __builtin_amdgcn_global_load_lds((const __attribute__((address_space(1))) void*)g,
                                   (__attribute__((address_space(3))) void*)l, 16, 0, 0);
}

// ---------- transpose + f32->bf16 convert ----------
// out row for input col r (r = c - c_off): (r>>4)*grp_stride + grp_off + (r&15)
// grp_stride=16, grp_off=0 -> identity (plain transpose)
__global__ __launch_bounds__(256) void k_transpose_cvt(
    const float* __restrict__ in, u16* __restrict__ out,
    int R, int C, size_t in_ls, size_t out_ls, int c_off, int grp_stride, int grp_off){
  __shared__ float tile[32][33];
  in  += (size_t)blockIdx.z * in_ls;
  out += (size_t)blockIdx.z * out_ls;
  int c0 = blockIdx.x * 32 + c_off, r0 = blockIdx.y * 32;
  int tx = threadIdx.x & 31, ty = threadIdx.x >> 5;  // ty 0..7
  #pragma unroll
  for (int i = 0; i < 32; i += 8)
    tile[ty + i][tx] = in[(size_t)(r0 + ty + i) * C + (c0 + tx)];
  __syncthreads();
  #pragma unroll
  for (int i = 0; i < 32; i += 8){
    int r = c0 - c_off + ty + i;
    int orow = (r >> 4) * grp_stride + grp_off + (r & 15);
    out[(size_t)orow * R + (r0 + tx)] = f2bf(tile[tx][ty + i]);
  }
}

// ---------- RMSNorm over D=1024, optional bf16 output ----------
__global__ __launch_bounds__(256) void k_rmsnorm(
    const float* __restrict__ x, const float* __restrict__ w,
    void* __restrict__ out, int out_bf16){
  int row = blockIdx.x;
  const float* xr = x + (size_t)row * 1024;
  int tid = threadIdx.x;
  float4 xv = ((const float4*)xr)[tid];
  float ss = xv.x*xv.x + xv.y*xv.y + xv.z*xv.z + xv.w*xv.w;
  #pragma unroll
  for (int off = 32; off >= 1; off >>= 1) ss += __shfl_xor(ss, off);
  __shared__ float red[4];
  if ((tid & 63) == 0) red[tid >> 6] = ss;
  __syncthreads();
  ss = red[0] + red[1] + red[2] + red[3];
  float s = rsqrtf(ss * (1.f/1024.f) + 1e-6f);
  float4 wv = ((const float4*)w)[tid];
  float o0 = xv.x*s*wv.x, o1 = xv.y*s*wv.y, o2 = xv.z*s*wv.z, o3 = xv.w*s*wv.w;
  if (out_bf16){
    u16* orow = (u16*)out + (size_t)row * 1024;
    uint2 pk;
    pk.x = (unsigned)f2bf(o0) | ((unsigned)f2bf(o1) << 16);
    pk.y = (unsigned)f2bf(o2) | ((unsigned)f2bf(o3) << 16);
    *(uint2*)(orow + tid * 4) = pk;
  } else {
    float* orow = (float*)out + (size_t)row * 1024;
    ((float4*)orow)[tid] = make_float4(o0, o1, o2, o3);
  }
}

// ---------- per-head RMSNorm (HD=64) + RoPE, f32 in -> bf16 out, one wave per (token,head) ----------
__global__ __launch_bounds__(256) void k_rope_bf16(
    const float* __restrict__ x, const float* __restrict__ nw,
    u16* __restrict__ dst, int nheads, int src_stride, int dst_stride){
  int gw = (blockIdx.x * 256 + threadIdx.x) >> 6;
  int lane = threadIdx.x & 63;
  int token = gw / nheads;
  int head = gw - token * nheads;
  int pos = token & 1023;  // S = 1024
  const float* p = x + (size_t)token * src_stride + head * 64;
  float v = p[lane];
  float ss = v * v;
  #pragma unroll
  for (int off = 32; off >= 1; off >>= 1) ss += __shfl_xor(ss, off);
  float r = rsqrtf(ss * (1.f/64.f) + 1e-6f);
  float xn = v * r * nw[lane];
  float partner = __shfl_xor(xn, 32);
  int i = lane & 31;
  float inv = exp2f(-19.931568569324174f * ((float)(2 * i) * (1.f/64.f)));
  float ang = (float)pos * inv;
  float sn, cs;
  sincosf(ang, &sn, &cs);
  float out = (lane < 32) ? (xn * cs - partner * sn) : (xn * cs + partner * sn);
  dst[(size_t)token * dst_stride + head * 64 + lane] = f2bf(out);
}

// ---------- bf16 MFMA GEMM, async-staged + double-buffered: C = A[M,K] @ Bt[N,K]^T ----------
// epi: 0 = store f32, 1 = Cf += acc (residual)
//      3 = fused GLU: Bt is stacked/interleaved [16 gate | 16 up] groups, N = 2*FFout;
//          writes Cb[row*3072 + col] = bf16(silu(g)*u)
__global__ __launch_bounds__(256) void k_gemm(
    const u16* __restrict__ A, const u16* __restrict__ Bt,
    float* __restrict__ Cf, u16* __restrict__ Cb,
    int M, int N, int K, int epi){
  __shared__ u16 As[2][128 * 32];   // 2 x 8KB
  __shared__ u16 Bs[2][128 * 32];
  int m0 = blockIdx.x * 128, n0 = blockIdx.y * 128;
  int tid = threadIdx.x;
  int lane = tid & 63, w = tid >> 6;
  int wm = w & 1, wn = w >> 1;
  int quad = lane >> 4, l16 = lane & 15;
  f32x4 acc[4][4];
  #pragma unroll
  for (int a = 0; a < 4; a++)
    #pragma unroll
    for (int b = 0; b < 4; b++) acc[a][b] = (f32x4){0.f, 0.f, 0.f, 0.f};

  // wave w owns chunks [w*128, w*128+128); lds dest = uniform base + lane*16
  auto stage = [&](int k0, int buf){
    #pragma unroll
    for (int j = 0; j < 2; j++){
      int cb = w * 128 + j * 64;
      int ci = cb + lane;
      int row = ci >> 2, cc = ci & 3;
      async16(A  + (size_t)(m0 + row) * K + k0 + cc * 8, &As[buf][cb * 8]);
      async16(Bt + (size_t)(n0 + row) * K + k0 + cc * 8, &Bs[buf][cb * 8]);
    }
  };

  stage(0, 0);
  int cur = 0;
  for (int k0 = 0; k0 < K; k0 += 32){
    __syncthreads();   // drains loads issued a full iteration ago (prologue for iter 0)
    if (k0 + 32 < K) stage(k0 + 32, cur ^ 1);
    bf16x8 af[4], bg[4];
    #pragma unroll
    for (int mi = 0; mi < 4; mi++)
      af[mi] = *(const bf16x8*)&As[cur][(wm * 64 + mi * 16 + l16) * 32 + quad * 8];
    #pragma unroll
    for (int ni = 0; ni < 4; ni++)
      bg[ni] = *(const bf16x8*)&Bs[cur][(wn * 64 + ni * 16 + l16) * 32 + quad * 8];
    #pragma unroll
    for (int mi = 0; mi < 4; mi++)
      #pragma unroll
      for (int ni = 0; ni < 4; ni++)
        acc[mi][ni] = __builtin_amdgcn_mfma_f32_16x16x32_bf16(af[mi], bg[ni], acc[mi][ni], 0, 0, 0);
    cur ^= 1;
  }

  if (epi == 3){
    int cbase = (n0 >> 1) + wn * 32;  // output col base (stacked rows /2)
    #pragma unroll
    for (int mi = 0; mi < 4; mi++){
      #pragma unroll
      for (int j = 0; j < 2; j++){
        #pragma unroll
        for (int r = 0; r < 4; r++){
          int row = m0 + wm * 64 + mi * 16 + quad * 4 + r;
          int col = cbase + j * 16 + l16;
          float g = acc[mi][2 * j][r];
          float u = acc[mi][2 * j + 1][r];
          float sg = g / (1.f + __expf(-g));
          Cb[(size_t)row * 3072 + col] = f2bf(sg * u);
        }
      }
    }
  } else {
    #pragma unroll
    for (int mi = 0; mi < 4; mi++){
      #pragma unroll
      for (int ni = 0; ni < 4; ni++){
        #pragma unroll
        for (int r = 0; r < 4; r++){
          int row = m0 + wm * 64 + mi * 16 + quad * 4 + r;
          int col = n0 + wn * 64 + ni * 16 + l16;
          size_t idx = (size_t)row * N + col;
          if (epi == 0) Cf[idx] = acc[mi][ni][r];
          else          Cf[idx] += acc[mi][ni][r];
        }
      }
    }
  }
}

// ---------- bf16 MFMA flash attention ----------
// qh: (B*S, 16, 64) bf16 ; kh_: (B*S, 8, 64) bf16 ; vth: (B, 8*64, S) bf16 (V transposed)
__global__ __launch_bounds__(256) void k_attn(
    const u16* __restrict__ qh, const u16* __restrict__ kh_,
    const u16* __restrict__ vth, const int* __restrict__ am,
    u16* __restrict__ ctx, int window){
  const int S = 1024, H = 16, HK = 8;
  __shared__ u16 Qs[64 * 72];      // [q][d], stride 72 (bank-safe)
  __shared__ u16 Ks[64 * 72];      // [key][d]
  __shared__ u16 Vt[64 * 72];      // [d][key]
  __shared__ u16 Ps[4][16 * 72];   // per-wave P [q][key]
  __shared__ int Ams[64];
  int b = blockIdx.z, h = blockIdx.y, q0 = blockIdx.x * 64;
  int kvh = h >> 1;
  int tid = threadIdx.x, w = tid >> 6, lane = tid & 63;
  int quad = lane >> 4, l16 = lane & 15;

  #pragma unroll
  for (int i = 0; i < 2; i++){
    int c = tid + i * 256;
    int row = c >> 3, dc = (c & 7) * 8;
    *(uint4*)&Qs[row * 72 + dc] =
        *(const uint4*)(qh + ((size_t)(b * S + q0 + row) * H + h) * 64 + dc);
  }
  __syncthreads();
  bf16x8 aq[2];
  aq[0] = *(const bf16x8*)&Qs[(w * 16 + l16) * 72 + quad * 8];
  aq[1] = *(const bf16x8*)&Qs[(w * 16 + l16) * 72 + 32 + quad * 8];

  f32x4 o[4];
  #pragma unroll
  for (int di = 0; di < 4; di++) o[di] = (f32x4){0.f, 0.f, 0.f, 0.f};
  float m_[4], l_[4];
  #pragma unroll
  for (int r = 0; r < 4; r++){ m_[r] = -1e30f; l_[r] = 0.f; }

  int t0 = 0, t1 = S / 64;
  if (window < S){
    t0 = (q0 > window) ? ((q0 - window) >> 6) : 0;
    int tt = (q0 + 63 + window) / 64 + 1;
    t1 = tt < (S / 64) ? tt : (S / 64);
  }

  for (int t = t0; t < t1; t++){
    __syncthreads();
    #pragma unroll
    for (int i = 0; i < 2; i++){
      int c = tid + i * 256;
      int row = c >> 3, dc = (c & 7) * 8;
      *(uint4*)&Ks[row * 72 + dc] =
          *(const uint4*)(kh_ + ((size_t)(b * S + t * 64 + row) * HK + kvh) * 64 + dc);
      *(uint4*)&Vt[row * 72 + dc] =
          *(const uint4*)(vth + ((size_t)b * 512 + kvh * 64 + row) * S + t * 64 + dc);
    }
    if (tid < 64) Ams[tid] = am[b * S + t * 64 + tid];
    __syncthreads();

    f32x4 sc[4];
    #pragma unroll
    for (int ni = 0; ni < 4; ni++){
      bf16x8 bk0 = *(const bf16x8*)&Ks[(ni * 16 + l16) * 72 + quad * 8];
      bf16x8 bk1 = *(const bf16x8*)&Ks[(ni * 16 + l16) * 72 + 32 + quad * 8];
      sc[ni] = __builtin_amdgcn_mfma_f32_16x16x32_bf16(aq[0], bk0, (f32x4){0.f,0.f,0.f,0.f}, 0, 0, 0);
      sc[ni] = __builtin_amdgcn_mfma_f32_16x16x32_bf16(aq[1], bk1, sc[ni], 0, 0, 0);
    }

    float rowmax[4];
    #pragma unroll
    for (int r = 0; r < 4; r++) rowmax[r] = -1e30f;
    #pragma unroll
    for (int ni = 0; ni < 4; ni++){
      int key = t * 64 + ni * 16 + l16;
      bool kval = Ams[ni * 16 + l16] > 0;
      #pragma unroll
      for (int r = 0; r < 4; r++){
        int qq = q0 + w * 16 + quad * 4 + r;
        int dlt = qq - key; if (dlt < 0) dlt = -dlt;
        bool valid = kval && (dlt <= window);
        float s = valid ? sc[ni][r] * 0.125f : -1e30f;
        sc[ni][r] = s;
        rowmax[r] = fmaxf(rowmax[r], s);
      }
    }
    #pragma unroll
    for (int off = 1; off <= 8; off <<= 1)
      #pragma unroll
      for (int r = 0; r < 4; r++) rowmax[r] = fmaxf(rowmax[r], __shfl_xor(rowmax[r], off));

    float alpha[4], rsum[4];
    #pragma unroll
    for (int r = 0; r < 4; r++){
      float nm = fmaxf(m_[r], rowmax[r]);
      alpha[r] = __expf(m_[r] - nm);
      m_[r] = nm;
      rsum[r] = 0.f;
    }
    #pragma unroll
    for (int ni = 0; ni < 4; ni++){
      #pragma unroll
      for (int r = 0; r < 4; r++){
        float s = sc[ni][r];
        float p = (s == -1e30f) ? 0.f : __expf(s - m_[r]);
        u16 pb = f2bf(p);
        rsum[r] += bf2f(pb);
        Ps[w][(quad * 4 + r) * 72 + ni * 16 + l16] = pb;
      }
    }
    #pragma unroll
    for (int off = 1; off <= 8; off <<= 1)
      #pragma unroll
      for (int r = 0; r < 4; r++) rsum[r] += __shfl_xor(rsum[r], off);
    #pragma unroll
    for (int r = 0; r < 4; r++) l_[r] = l_[r] * alpha[r] + rsum[r];
    #pragma unroll
    for (int di = 0; di < 4; di++)
      #pragma unroll
      for (int r = 0; r < 4; r++) o[di][r] *= alpha[r];

    __syncthreads();

    bf16x8 ap0 = *(const bf16x8*)&Ps[w][l16 * 72 + quad * 8];
    bf16x8 ap1 = *(const bf16x8*)&Ps[w][l16 * 72 + 32 + quad * 8];
    #pragma unroll
    for (int di = 0; di < 4; di++){
      bf16x8 bv0 = *(const bf16x8*)&Vt[(di * 16 + l16) * 72 + quad * 8];
      bf16x8 bv1 = *(const bf16x8*)&Vt[(di * 16 + l16) * 72 + 32 + quad * 8];
      o[di] = __builtin_amdgcn_mfma_f32_16x16x32_bf16(ap0, bv0, o[di], 0, 0, 0);
      o[di] = __builtin_amdgcn_mfma_f32_16x16x32_bf16(ap1, bv1, o[di], 0, 0, 0);
    }
  }

  #pragma unroll
  for (int di = 0; di < 4; di++){
    #pragma unroll
    for (int r = 0; r < 4; r++){
      int qq = q0 + w * 16 + quad * 4 + r;
      float val = o[di][r] / fmaxf(l_[r], 1e-30f);
      ctx[(size_t)(b * S + qq) * 1024 + h * 64 + di * 16 + l16] = f2bf(val);
    }
  }
}

extern "C" void kernel_launch(void* const* d_in, const int* in_sizes, int n_in,
                              void* d_out, int out_size, void* d_ws, size_t ws_size,
                              hipStream_t stream){
  const int L = 4, D = 1024, H = 16, HK = 8, HD = 64, FF = 3072, B = 4, S = 1024;
  const int M = B * S;  // 4096

  const float* emb = (const float*)d_in[0];
  const float* wq  = (const float*)d_in[1];
  const float* wk  = (const float*)d_in[2];
  const float* wv  = (const float*)d_in[3];
  const float* wo  = (const float*)d_in[4];
  const float* qnw = (const float*)d_in[5];
  const float* knw = (const float*)d_in[6];
  const float* ln1 = (const float*)d_in[7];
  const float* ln2 = (const float*)d_in[8];
  const float* wg  = (const float*)d_in[9];
  const float* wu  = (const float*)d_in[10];
  const float* wd  = (const float*)d_in[11];
  const float* nw  = (const float*)d_in[12];
  const int*   am  = (const int*)d_in[13];
  float* h = (float*)d_out;

  char* ws = (char*)d_ws;
  size_t off = 0;
  auto alloc = [&](size_t bytes) -> void* {
    void* p = ws + off;
    off += (bytes + 255) & ~(size_t)255;
    return p;
  };
  u16* wqkvT = (u16*)alloc((size_t)L * 2048 * D * 2);  // rows: [q 1024 | k 512 | v 512], K-major
  u16* woT   = (u16*)alloc((size_t)L * D * (H * HD) * 2);
  u16* wguT  = (u16*)alloc((size_t)L * 2 * FF * D * 2); // interleaved [16 gate | 16 up] groups
  u16* wdT   = (u16*)alloc((size_t)L * D * FF * 2);
  u16* nbf   = (u16*)alloc((size_t)M * D * 2);
  u16* ctxb  = (u16*)alloc((size_t)M * D * 2);
  float* qkvb = (float*)alloc((size_t)M * 2048 * 4);   // [q 1024 | k 512 | v 512]
  u16* actb  = (u16*)alloc((size_t)M * FF * 2);
  u16* qbh   = (u16*)alloc((size_t)M * 1024 * 2);
  u16* kbh   = (u16*)alloc((size_t)M * 512 * 2);
  u16* vth   = (u16*)alloc((size_t)B * 512 * S * 2);
  (void)ws_size; (void)in_sizes; (void)n_in; (void)out_size;

  hipMemcpyAsync(h, emb, (size_t)M * D * 4, hipMemcpyDeviceToDevice, stream);

  // weights -> bf16, transposed (N, K)
  k_transpose_cvt<<<dim3(32, 32, L), 256, 0, stream>>>(wq, wqkvT,                  D, 1024, (size_t)D*1024, (size_t)2048*D, 0, 16, 0);
  k_transpose_cvt<<<dim3(16, 32, L), 256, 0, stream>>>(wk, wqkvT + (size_t)1024*D, D, 512,  (size_t)D*512,  (size_t)2048*D, 0, 16, 0);
  k_transpose_cvt<<<dim3(16, 32, L), 256, 0, stream>>>(wv, wqkvT + (size_t)1536*D, D, 512,  (size_t)D*512,  (size_t)2048*D, 0, 16, 0);
  k_transpose_cvt<<<dim3(32, 32, L), 256, 0, stream>>>(wo, woT, 1024, D, (size_t)1024*D, (size_t)D*1024, 0, 16, 0);
  // gate/up interleaved into stacked (6144, 1024): gate col c -> row (c>>4)*32+(c&15), up -> +16
  k_transpose_cvt<<<dim3(96, 32, L), 256, 0, stream>>>(wg, wguT, D, FF, (size_t)D*FF, (size_t)2*FF*D, 0, 32, 0);
  k_transpose_cvt<<<dim3(96, 32, L), 256, 0, stream>>>(wu, wguT, D, FF, (size_t)D*FF, (size_t)2*FF*D, 0, 32, 16);
  k_transpose_cvt<<<dim3(32, 96, L), 256, 0, stream>>>(wd, wdT, FF, D, (size_t)FF*D, (size_t)D*FF, 0, 16, 0);

  for (int l = 0; l < L; l++){
    const u16* wqkvTl = wqkvT + (size_t)l * 2048 * D;
    const u16* woTl   = woT  + (size_t)l * D * 1024;
    const u16* wguTl  = wguT + (size_t)l * 2 * FF * D;
    const u16* wdTl   = wdT  + (size_t)l * D * FF;

    k_rmsnorm<<<M, 256, 0, stream>>>(h, ln1 + l * D, nbf, 1);
    k_gemm<<<dim3(M/128, 2048/128), 256, 0, stream>>>(nbf, wqkvTl, qkvb, nullptr, M, 2048, D, 0);
    k_rope_bf16<<<(M * H) / 4, 256, 0, stream>>>(qkvb,         qnw + l * HD, qbh, H,  2048, 1024);
    k_rope_bf16<<<(M * HK) / 4, 256, 0, stream>>>(qkvb + 1024, knw + l * HD, kbh, HK, 2048, 512);
    k_transpose_cvt<<<dim3(16, 32, B), 256, 0, stream>>>(qkvb, vth, S, 2048, (size_t)S*2048, (size_t)512*S, 1536, 16, 0);
    k_attn<<<dim3(S/64, H, B), 256, 0, stream>>>(qbh, kbh, vth, am, ctxb, (l & 1) ? 12 : 2048);
    k_gemm<<<dim3(M/128, 1024/128), 256, 0, stream>>>(ctxb, woTl, h, nullptr, M, D, 1024, 1);
    k_rmsnorm<<<M, 256, 0, stream>>>(h, ln2 + l * D, nbf, 1);
    k_gemm<<<dim3(M/128, (2*FF)/128), 256, 0, stream>>>(nbf, wguTl, nullptr, actb, M, 2*FF, D, 3);
    k_gemm<<<dim3(M/128, D/128), 256, 0, stream>>>(actb, wdTl, h, nullptr, M, D, FF, 1);
  }
  k_rmsnorm<<<M, 256, 0, stream>>>(h, nw, h, 0);
}